// Round 2
// baseline (849.972 us; speedup 1.0000x reference)
//
#include <hip/hip_runtime.h>

// Dynamic range compressor:
//   gr[t]  = max(20*log10(|x|+1e-8) - thr, 0) * (1 - 1/ratio)     (parallel)
//   g[0]=0; g[t] = (1-a)*g[t-1] + a*gr[t], a = att if gr[t]>g else rel (serial)
//   out[t] = sign(x)*(|x|+1e-8)*10^((mk - g[t])/20)
//
// Parallelized via chunked scan with warm-up: the recurrence is a monotone
// contraction (slope <= 1-alpha_release per step), so a W-sample warm-up from
// g=0 converges to the true state within 22dB * exp(-W*rate). W=16384.
//
// NOTE: no <math.h> — glibc's __MATHCALL macros collide with HIP's
// __expf/__log2f/__exp2f intrinsics. Use __builtin_* (lower to
// v_log_f32 / v_exp_f32 on gfx950).

#define T_LEN   (1 << 20)
#define W_WARM  16384
#define C_CHUNK 512

__global__ __launch_bounds__(256) void gr_kernel(
    const float* __restrict__ audio,
    const float* __restrict__ p_thr,
    const float* __restrict__ p_ratio,
    float* __restrict__ gr, int n4) {
  const float thr = p_thr[0];
  const float r1  = 1.0f - 1.0f / p_ratio[0];
  const float K   = 6.0205999132796239f * r1;   // 20*log10(2) * r1
  const float Cc  = -thr * r1;
  int i = blockIdx.x * blockDim.x + threadIdx.x;
  const int stride = gridDim.x * blockDim.x;
  const float4* a4 = (const float4*)audio;
  float4* g4 = (float4*)gr;
  for (; i < n4; i += stride) {
    float4 v = a4[i];
    float4 o;
    o.x = fmaxf(fmaf(K, __builtin_log2f(fabsf(v.x) + 1e-8f), Cc), 0.0f);
    o.y = fmaxf(fmaf(K, __builtin_log2f(fabsf(v.y) + 1e-8f), Cc), 0.0f);
    o.z = fmaxf(fmaf(K, __builtin_log2f(fabsf(v.z) + 1e-8f), Cc), 0.0f);
    o.w = fmaxf(fmaf(K, __builtin_log2f(fabsf(v.w) + 1e-8f), Cc), 0.0f);
    g4[i] = o;
  }
}

template <bool SPLIT>
__global__ __launch_bounds__(64) void comp_kernel(
    const float* __restrict__ audio,
    const float* __restrict__ grbuf,
    const float* __restrict__ p_thr,
    const float* __restrict__ p_ratio,
    const float* __restrict__ p_att,
    const float* __restrict__ p_rel,
    const float* __restrict__ p_mk,
    float* __restrict__ out, int total_chunks) {
  const int tid = blockIdx.x * blockDim.x + threadIdx.x;
  if (tid >= total_chunks) return;

  const int chunks_per_ch = T_LEN / C_CHUNK;
  const int ch = tid / chunks_per_ch;
  const int t0 = (tid - ch * chunks_per_ch) * C_CHUNK;

  const float* __restrict__ A = audio + (size_t)ch * T_LEN;
  const float* __restrict__ G = grbuf + (size_t)ch * T_LEN;
  float* __restrict__ O = out + (size_t)ch * T_LEN;

  const float L2E = 1.4426950408889634f;        // log2(e)
  const float aatt = 1.0f - __builtin_exp2f(-L2E / (p_att[0] * 48000.0f));
  const float arel = 1.0f - __builtin_exp2f(-L2E / (p_rel[0] * 48000.0f));
  const float mk   = p_mk[0];
  const float thr  = p_thr[0];
  const float r1   = 1.0f - 1.0f / p_ratio[0];
  const float K    = 6.0205999132796239f * r1;
  const float Cc   = -thr * r1;
  const float EK   = 0.16609640474436813f;      // log2(10)/20

  float g = 0.0f;

  auto grv_of = [&](float x) {
    return fmaxf(fmaf(K, __builtin_log2f(fabsf(x) + 1e-8f), Cc), 0.0f);
  };
  auto upd = [&](float grv) {
    float d  = grv - g;
    float t1 = fmaf(aatt, d, g);
    float t2 = fmaf(arel, d, g);
    g = fmaxf(t1, t2);   // gr>g -> attack branch is larger; else release
  };
  auto outv = [&](float x) {
    float e   = (mk - g) * EK;
    float mag = (fabsf(x) + 1e-8f) * __builtin_exp2f(e);
    float o   = copysignf(mag, x);
    return (x == 0.0f) ? 0.0f : o;
  };

  int start = t0 - W_WARM;
  if (start < 0) start = 0;
  int t = start;

  // Peel the quad containing t==0 (g[0] = 0, no update at t=0).
  if (start == 0) {
    float4 q;
    if (SPLIT) {
      q = *(const float4*)(G);
    } else {
      float4 x = *(const float4*)(A);
      q.x = grv_of(x.x); q.y = grv_of(x.y); q.z = grv_of(x.z); q.w = grv_of(x.w);
    }
    if (t0 == 0) {
      float4 x = *(const float4*)(A);
      float4 r;
      /* t=0: g stays 0 */ r.x = outv(x.x);
      upd(q.y);            r.y = outv(x.y);
      upd(q.z);            r.z = outv(x.z);
      upd(q.w);            r.w = outv(x.w);
      *(float4*)(O) = r;
    } else {
      upd(q.y); upd(q.z); upd(q.w);
    }
    t = 4;
  }

  // Warm-up: chain only.
  for (; t < t0; t += 4) {
    float4 q;
    if (SPLIT) {
      q = *(const float4*)(G + t);
    } else {
      float4 x = *(const float4*)(A + t);
      q.x = grv_of(x.x); q.y = grv_of(x.y); q.z = grv_of(x.z); q.w = grv_of(x.w);
    }
    upd(q.x); upd(q.y); upd(q.z); upd(q.w);
  }

  // Output region.
  const int tend = t0 + C_CHUNK;
  for (; t < tend; t += 4) {
    float4 x = *(const float4*)(A + t);
    float4 q;
    if (SPLIT) {
      q = *(const float4*)(G + t);
    } else {
      q.x = grv_of(x.x); q.y = grv_of(x.y); q.z = grv_of(x.z); q.w = grv_of(x.w);
    }
    float4 r;
    upd(q.x); r.x = outv(x.x);
    upd(q.y); r.y = outv(x.y);
    upd(q.z); r.z = outv(x.z);
    upd(q.w); r.w = outv(x.w);
    *(float4*)(O + t) = r;
  }
}

extern "C" void kernel_launch(void* const* d_in, const int* in_sizes, int n_in,
                              void* d_out, int out_size, void* d_ws, size_t ws_size,
                              hipStream_t stream) {
  const float* audio   = (const float*)d_in[0];
  const float* p_thr   = (const float*)d_in[1];
  const float* p_ratio = (const float*)d_in[2];
  const float* p_att   = (const float*)d_in[3];
  const float* p_rel   = (const float*)d_in[4];
  const float* p_mk    = (const float*)d_in[5];
  float* outp = (float*)d_out;

  const int n = in_sizes[0];                // 16 * 2^20
  const int total_chunks = n / C_CHUNK;     // 32768
  const size_t ws_need = (size_t)n * sizeof(float);

  if (ws_size >= ws_need) {
    float* gr = (float*)d_ws;
    const int n4 = n / 4;
    gr_kernel<<<2048, 256, 0, stream>>>(audio, p_thr, p_ratio, gr, n4);
    comp_kernel<true><<<(total_chunks + 63) / 64, 64, 0, stream>>>(
        audio, gr, p_thr, p_ratio, p_att, p_rel, p_mk, outp, total_chunks);
  } else {
    comp_kernel<false><<<(total_chunks + 63) / 64, 64, 0, stream>>>(
        audio, (const float*)nullptr, p_thr, p_ratio, p_att, p_rel, p_mk, outp,
        total_chunks);
  }
}

// Round 3
// 391.311 us; speedup vs baseline: 2.1721x; 2.1721x over previous
//
#include <hip/hip_runtime.h>

// Dynamic range compressor:
//   gr[t]  = max(20*log10(|x|+1e-8) - thr, 0) * (1 - 1/ratio)     (parallel)
//   g[0]=0; g[t] = (1-a)*g[t-1] + a*gr[t], a = att if gr[t]>g else rel (serial)
//   out[t] = sign(x)*(|x|+1e-8)*10^((mk - g[t])/20)
//
// Chunked scan with warm-up (contraction => W-sample warm-up from g=0
// converges within ~22dB*exp(-W*rate)). C=512, W=16384, 32768 threads.
// Round 3: explicit register double-buffered pipelining of the gr loads —
// round 2 showed 844us @ VALUBusy 8.7% (every scattered 16B load's latency
// naked on the serial chain). Loads are chain-independent -> hide them.
//
// NOTE: no <math.h> — glibc __MATHCALL macros collide with HIP intrinsics;
// use __builtin_log2f/__builtin_exp2f (lower to v_log_f32/v_exp_f32).

#define T_LEN   (1 << 20)
#define W_WARM  16384
#define C_CHUNK 512

__global__ __launch_bounds__(256) void gr_kernel(
    const float* __restrict__ audio,
    const float* __restrict__ p_thr,
    const float* __restrict__ p_ratio,
    float* __restrict__ gr, int n4) {
  const float thr = p_thr[0];
  const float r1  = 1.0f - 1.0f / p_ratio[0];
  const float K   = 6.0205999132796239f * r1;   // 20*log10(2) * r1
  const float Cc  = -thr * r1;
  int i = blockIdx.x * blockDim.x + threadIdx.x;
  const int stride = gridDim.x * blockDim.x;
  const float4* a4 = (const float4*)audio;
  float4* g4 = (float4*)gr;
  for (; i < n4; i += stride) {
    float4 v = a4[i];
    float4 o;
    o.x = fmaxf(fmaf(K, __builtin_log2f(fabsf(v.x) + 1e-8f), Cc), 0.0f);
    o.y = fmaxf(fmaf(K, __builtin_log2f(fabsf(v.y) + 1e-8f), Cc), 0.0f);
    o.z = fmaxf(fmaf(K, __builtin_log2f(fabsf(v.z) + 1e-8f), Cc), 0.0f);
    o.w = fmaxf(fmaf(K, __builtin_log2f(fabsf(v.w) + 1e-8f), Cc), 0.0f);
    g4[i] = o;
  }
}

__global__ __launch_bounds__(64) void comp_kernel(
    const float* __restrict__ audio,
    const float* __restrict__ grbuf,
    const float* __restrict__ p_att,
    const float* __restrict__ p_rel,
    const float* __restrict__ p_mk,
    float* __restrict__ out, int total_chunks) {
  const int tid = blockIdx.x * blockDim.x + threadIdx.x;
  if (tid >= total_chunks) return;

  const int chunks_per_ch = T_LEN / C_CHUNK;
  const int ch = tid / chunks_per_ch;
  const int t0 = (tid - ch * chunks_per_ch) * C_CHUNK;

  const float* __restrict__ A = audio + (size_t)ch * T_LEN;
  const float* __restrict__ G = grbuf + (size_t)ch * T_LEN;
  float* __restrict__ O = out + (size_t)ch * T_LEN;

  const float L2E = 1.4426950408889634f;        // log2(e)
  const float aatt = 1.0f - __builtin_exp2f(-L2E / (p_att[0] * 48000.0f));
  const float arel = 1.0f - __builtin_exp2f(-L2E / (p_rel[0] * 48000.0f));
  const float mk   = p_mk[0];
  const float EK   = 0.16609640474436813f;      // log2(10)/20

  float g = 0.0f;

  auto upd = [&](float grv) {
    float d  = grv - g;
    float t1 = fmaf(aatt, d, g);
    float t2 = fmaf(arel, d, g);
    g = fmaxf(t1, t2);   // gr>g -> attack branch is larger; else release
  };
  auto outv = [&](float x) {
    float e   = (mk - g) * EK;
    float mag = (fabsf(x) + 1e-8f) * __builtin_exp2f(e);
    float o   = copysignf(mag, x);
    return (x == 0.0f) ? 0.0f : o;
  };

  int start = t0 - W_WARM;
  if (start < 0) start = 0;
  int t = start;

  // Peel the quad containing t==0 (g[0] = 0, no update at t=0).
  if (start == 0) {
    float4 q = *(const float4*)(G);
    if (t0 == 0) {
      float4 x = *(const float4*)(A);
      float4 r;
      /* t=0: g stays 0 */ r.x = outv(x.x);
      upd(q.y);            r.y = outv(x.y);
      upd(q.z);            r.z = outv(x.z);
      upd(q.w);            r.w = outv(x.w);
      *(float4*)(O) = r;
    } else {
      upd(q.y); upd(q.z); upd(q.w);
    }
    t = 4;
  }

  // ---- Warm-up: chain only, software-pipelined over 32-sample blocks. ----
  {
    const int nblk = (t0 - t) >> 5;
    if (nblk > 0) {
      const float* Gp = G + t;
      float4 cur[8];
#pragma unroll
      for (int i = 0; i < 8; ++i) cur[i] = *(const float4*)(Gp + 4 * i);
      for (int b = 1; b < nblk; ++b) {
        float4 nxt[8];
        const float* Gb = Gp + (b << 5);
#pragma unroll
        for (int i = 0; i < 8; ++i) nxt[i] = *(const float4*)(Gb + 4 * i);
#pragma unroll
        for (int i = 0; i < 8; ++i) {
          upd(cur[i].x); upd(cur[i].y); upd(cur[i].z); upd(cur[i].w);
        }
#pragma unroll
        for (int i = 0; i < 8; ++i) cur[i] = nxt[i];
      }
#pragma unroll
      for (int i = 0; i < 8; ++i) {
        upd(cur[i].x); upd(cur[i].y); upd(cur[i].z); upd(cur[i].w);
      }
      t += nblk << 5;
    }
    for (; t < t0; t += 4) {   // remainder (start==0 threads only)
      float4 q = *(const float4*)(G + t);
      upd(q.x); upd(q.y); upd(q.z); upd(q.w);
    }
  }

  // ---- Output region: pipelined over 32-sample blocks, both streams. ----
  {
    const int tend = t0 + C_CHUNK;
    const int nblk = (tend - t) >> 5;
    if (nblk > 0) {
      const float* Ap = A + t;
      const float* Gp = G + t;
      float* Op = O + t;
      float4 ca[8], cg[8];
#pragma unroll
      for (int i = 0; i < 8; ++i) {
        ca[i] = *(const float4*)(Ap + 4 * i);
        cg[i] = *(const float4*)(Gp + 4 * i);
      }
      for (int b = 1; b < nblk; ++b) {
        float4 na[8], ng[8];
        const float* Ab = Ap + (b << 5);
        const float* Gb = Gp + (b << 5);
#pragma unroll
        for (int i = 0; i < 8; ++i) {
          na[i] = *(const float4*)(Ab + 4 * i);
          ng[i] = *(const float4*)(Gb + 4 * i);
        }
        float* Ob = Op + ((b - 1) << 5);
#pragma unroll
        for (int i = 0; i < 8; ++i) {
          float4 r;
          upd(cg[i].x); r.x = outv(ca[i].x);
          upd(cg[i].y); r.y = outv(ca[i].y);
          upd(cg[i].z); r.z = outv(ca[i].z);
          upd(cg[i].w); r.w = outv(ca[i].w);
          *(float4*)(Ob + 4 * i) = r;
        }
#pragma unroll
        for (int i = 0; i < 8; ++i) { ca[i] = na[i]; cg[i] = ng[i]; }
      }
      float* Ob = Op + ((nblk - 1) << 5);
#pragma unroll
      for (int i = 0; i < 8; ++i) {
        float4 r;
        upd(cg[i].x); r.x = outv(ca[i].x);
        upd(cg[i].y); r.y = outv(ca[i].y);
        upd(cg[i].z); r.z = outv(ca[i].z);
        upd(cg[i].w); r.w = outv(ca[i].w);
        *(float4*)(Ob + 4 * i) = r;
      }
      t += nblk << 5;
    }
    for (; t < tend; t += 4) {   // remainder
      float4 x = *(const float4*)(A + t);
      float4 q = *(const float4*)(G + t);
      float4 r;
      upd(q.x); r.x = outv(x.x);
      upd(q.y); r.y = outv(x.y);
      upd(q.z); r.z = outv(x.z);
      upd(q.w); r.w = outv(x.w);
      *(float4*)(O + t) = r;
    }
  }
}

extern "C" void kernel_launch(void* const* d_in, const int* in_sizes, int n_in,
                              void* d_out, int out_size, void* d_ws, size_t ws_size,
                              hipStream_t stream) {
  const float* audio   = (const float*)d_in[0];
  const float* p_thr   = (const float*)d_in[1];
  const float* p_ratio = (const float*)d_in[2];
  const float* p_att   = (const float*)d_in[3];
  const float* p_rel   = (const float*)d_in[4];
  const float* p_mk    = (const float*)d_in[5];
  float* outp = (float*)d_out;

  const int n = in_sizes[0];                // 16 * 2^20
  const int total_chunks = n / C_CHUNK;     // 32768
  float* gr = (float*)d_ws;                 // ws_size is ample (>= n floats)
  const int n4 = n / 4;

  gr_kernel<<<2048, 256, 0, stream>>>(audio, p_thr, p_ratio, gr, n4);
  comp_kernel<<<(total_chunks + 63) / 64, 64, 0, stream>>>(
      audio, gr, p_att, p_rel, p_mk, outp, total_chunks);
}

// Round 4
// 237.052 us; speedup vs baseline: 3.5856x; 1.6507x over previous
//
#include <hip/hip_runtime.h>

// Dynamic range compressor, chunked-scan with warm-up.
//   gr[t]  = max(20*log10(|x|+1e-8) - thr, 0)*(1-1/ratio)          (parallel)
//   g[0]=0; g[t] = (1-a)*g[t-1] + a*gr[t], a = att if gr[t]>g else rel
//   out[t] = sign(x)*(|x|+1e-8)*10^((mk - g[t])/20)
// Contraction => W-sample warm-up from g=0 converges (measured 3.9e-3 @ W=16384;
// W=12288 => ~9e-3, threshold 3.08e-2). C=512, 32768 threads.
// Round 4: depth-4 modulo software pipeline on warm-up loads (round 3 was
// depth-1: 53 cyc/sample vs 12-cyc chain floor), gr in fp16 (half traffic),
// gr[ch][0]:=0 (ref never uses it; upd(0) from g=0 is a no-op -> no peel).
// NOTE: no <math.h> (glibc __MATHCALL collides with HIP intrinsics).

#define T_LEN   (1 << 20)
#define W_WARM  12288
#define C_CHUNK 512

typedef _Float16 half_t;
typedef _Float16 half8 __attribute__((ext_vector_type(8)));
typedef float    fvec4 __attribute__((ext_vector_type(4)));

__global__ __launch_bounds__(256) void gr_kernel(
    const float* __restrict__ audio,
    const float* __restrict__ p_thr,
    const float* __restrict__ p_ratio,
    half_t* __restrict__ gr, int n8) {
  const float thr = p_thr[0];
  const float r1  = 1.0f - 1.0f / p_ratio[0];
  const float K   = 6.0205999132796239f * r1;   // 20*log10(2) * r1
  const float Cc  = -thr * r1;
  int i = blockIdx.x * blockDim.x + threadIdx.x;
  const int stride = gridDim.x * blockDim.x;
  const fvec4* a4 = (const fvec4*)audio;
  half8* g8 = (half8*)gr;
  for (; i < n8; i += stride) {
    fvec4 v0 = a4[2 * i];
    fvec4 v1 = a4[2 * i + 1];
    half8 o;
#pragma unroll
    for (int j = 0; j < 8; ++j) {
      float x = (j < 4) ? v0[j & 3] : v1[j & 3];
      o[j] = (half_t)fmaxf(fmaf(K, __builtin_log2f(fabsf(x) + 1e-8f), Cc), 0.0f);
    }
    if ((i & (T_LEN / 8 - 1)) == 0) o[0] = (half_t)0.0f;  // gr[ch][0] unused by ref
    g8[i] = o;
  }
}

__global__ __launch_bounds__(64) void comp_kernel(
    const float* __restrict__ audio,
    const half_t* __restrict__ grbuf,
    const float* __restrict__ p_att,
    const float* __restrict__ p_rel,
    const float* __restrict__ p_mk,
    float* __restrict__ out, int total_chunks) {
  const int tid = blockIdx.x * blockDim.x + threadIdx.x;
  if (tid >= total_chunks) return;

  const int chunks_per_ch = T_LEN / C_CHUNK;
  const int ch = tid / chunks_per_ch;
  const int t0 = (tid - ch * chunks_per_ch) * C_CHUNK;

  const float*  __restrict__ A = audio + (size_t)ch * T_LEN;
  const half_t* __restrict__ G = grbuf + (size_t)ch * T_LEN;
  float*        __restrict__ O = out + (size_t)ch * T_LEN;

  const float L2E = 1.4426950408889634f;        // log2(e)
  const float aatt = 1.0f - __builtin_exp2f(-L2E / (p_att[0] * 48000.0f));
  const float arel = 1.0f - __builtin_exp2f(-L2E / (p_rel[0] * 48000.0f));
  const float mk   = p_mk[0];
  const float EK   = 0.16609640474436813f;      // log2(10)/20

  float g = 0.0f;

  auto upd = [&](float grv) {
    float d  = grv - g;
    float t1 = fmaf(aatt, d, g);
    float t2 = fmaf(arel, d, g);
    g = fmaxf(t1, t2);   // gr>g -> attack branch larger; else release
  };
  auto outv = [&](float x) {
    float e   = (mk - g) * EK;
    float mag = (fabsf(x) + 1e-8f) * __builtin_exp2f(e);
    float o   = copysignf(mag, x);
    return (x == 0.0f) ? 0.0f : o;
  };

  int start = t0 - W_WARM;
  if (start < 0) start = 0;
  // start and t0 are both multiples of 32; nblk = multiple of 16 (0 for chunk 0).

  // ---- Warm-up: 32-sample blocks, depth-4 modulo pipeline (prefetch 3). ----
  {
    const int nblk = (t0 - start) >> 5;
    if (nblk > 0) {                       // all active lanes have nblk >= 16
      const half8* Gp8 = (const half8*)(G + start);   // 4 half8 per block
      half8 bA[4], bB[4], bC[4], bD[4];
      auto ld = [&](half8 (&buf)[4], int b) {
        const half8* p = Gp8 + 4 * b;
#pragma unroll
        for (int i = 0; i < 4; ++i) buf[i] = p[i];
      };
      auto proc = [&](const half8 (&buf)[4]) {
#pragma unroll
        for (int i = 0; i < 4; ++i)
#pragma unroll
          for (int j = 0; j < 8; ++j) upd((float)buf[i][j]);
      };
      ld(bA, 0); ld(bB, 1); ld(bC, 2);
#pragma unroll 1
      for (int b = 0; b + 4 <= nblk; b += 4) {
        // final iteration's last 3 loads overrun into [t0, t0+96): in-bounds, unused
        ld(bD, b + 3); proc(bA);
        ld(bA, b + 4); proc(bB);
        ld(bB, b + 5); proc(bC);
        ld(bC, b + 6); proc(bD);
      }
    }
  }

  // ---- Output region: 16 blocks of 32 samples, depth-2 pipeline. ----
  {
    const fvec4* Ap = (const fvec4*)(A + t0);   // 8 fvec4 per block
    const half8* Gp = (const half8*)(G + t0);   // 4 half8 per block
    fvec4* Op = (fvec4*)(O + t0);

    fvec4 a0[8], a1[8];
    half8 g0[4], g1[4];
    auto lda = [&](fvec4 (&ab)[8], half8 (&gb)[4], int b) {
#pragma unroll
      for (int i = 0; i < 8; ++i) ab[i] = Ap[8 * b + i];
#pragma unroll
      for (int i = 0; i < 4; ++i) gb[i] = Gp[4 * b + i];
    };
    auto emit = [&](const fvec4 (&ab)[8], const half8 (&gb)[4], int b) {
      fvec4 r[8];
#pragma unroll
      for (int s = 0; s < 32; ++s) {
        upd((float)gb[s >> 3][s & 7]);
        r[s >> 2][s & 3] = outv(ab[s >> 2][s & 3]);
      }
#pragma unroll
      for (int i = 0; i < 8; ++i) Op[8 * b + i] = r[i];
    };

    lda(a0, g0, 0);
#pragma unroll 1
    for (int b = 0; b < 16; b += 2) {
      lda(a1, g1, b + 1);
      emit(a0, g0, b);
      int b2 = (b + 2 < 16) ? b + 2 : 15;  // clamp: avoid OOB read at channel end
      lda(a0, g0, b2);
      emit(a1, g1, b + 1);
    }
  }
}

extern "C" void kernel_launch(void* const* d_in, const int* in_sizes, int n_in,
                              void* d_out, int out_size, void* d_ws, size_t ws_size,
                              hipStream_t stream) {
  const float* audio   = (const float*)d_in[0];
  const float* p_thr   = (const float*)d_in[1];
  const float* p_ratio = (const float*)d_in[2];
  const float* p_att   = (const float*)d_in[3];
  const float* p_rel   = (const float*)d_in[4];
  const float* p_mk    = (const float*)d_in[5];
  float* outp = (float*)d_out;

  const int n = in_sizes[0];                // 16 * 2^20
  const int total_chunks = n / C_CHUNK;     // 32768
  half_t* gr = (half_t*)d_ws;               // n * 2 bytes <= ws_size
  const int n8 = n / 8;

  gr_kernel<<<2048, 256, 0, stream>>>(audio, p_thr, p_ratio, gr, n8);
  comp_kernel<<<(total_chunks + 63) / 64, 64, 0, stream>>>(
      audio, gr, p_att, p_rel, p_mk, outp, total_chunks);
}

// Round 5
// 173.064 us; speedup vs baseline: 4.9113x; 1.3697x over previous
//
#include <hip/hip_runtime.h>

// Dynamic range compressor via composed piecewise-linear scan operators.
//   gr[t]  = max(20*log10(|x|+1e-8) - thr, 0)*(1-1/ratio)
//   g[0]=0; g[t] = (1-a)*g[t-1] + a*gr[t],  a = att if gr[t]>g[t-1] else rel
//   out[t] = sign(x)*(|x|+1e-8)*10^((mk - g[t])/20)
// Per-sample update = max of two affine fns of g (attack/release lines).
// Max-affine fns compose exactly; slopes of an m-fold composition are
// b1^k*b2^(m-k) (m+1 classes; parallel lines merge via offline intercept max).
// So each 4-sample block is EXACTLY g' = max_{k=0..4}(I_k + S_k*g); the 5
// intercepts are data-parallel precomputed (pre_kernel) and stored fp16.
// Warm-up (only final g needed) runs 1 composed step / 4 samples.
// Chunked scan: C=1024, warm-up W=12288 (contraction => truncation ~3e-3,
// threshold 3.08e-2; measured error has sat at the bf16-output floor 2^-8).
// NOTE: no <math.h> (glibc __MATHCALL collides with HIP intrinsics).

#define T_LEN   (1 << 20)
#define W_WARM  12288
#define C_CHUNK 1024
#define RECS_PER_CH (T_LEN / 32)   // 32768 records (32 samples each) per channel

typedef _Float16 half_t;
typedef _Float16 half8 __attribute__((ext_vector_type(8)));
typedef float    fvec4 __attribute__((ext_vector_type(4)));

__device__ __forceinline__ float fmax3f(float a, float b, float c) {
  return fmaxf(fmaxf(a, b), c);   // clang fuses to v_max3_f32
}

// One thread per 32-sample record: compute gr, compose pairs->quads, store
// 5 half8 per record; h[j][q] = intercept class j (slope S_j) of quad q.
__global__ __launch_bounds__(256) void pre_kernel(
    const float* __restrict__ audio,
    const float* __restrict__ p_thr,
    const float* __restrict__ p_ratio,
    const float* __restrict__ p_att,
    const float* __restrict__ p_rel,
    half8* __restrict__ recs, int nrec_total) {
  int rec = blockIdx.x * blockDim.x + threadIdx.x;
  if (rec >= nrec_total) return;
  const float thr = p_thr[0];
  const float r1  = 1.0f - 1.0f / p_ratio[0];
  const float K   = 6.0205999132796239f * r1;    // 20*log10(2)*r1
  const float Cc  = -thr * r1;
  const float L2E = 1.4426950408889634f;
  const float aatt = 1.0f - __builtin_exp2f(-L2E / (p_att[0] * 48000.0f));
  const float arel = 1.0f - __builtin_exp2f(-L2E / (p_rel[0] * 48000.0f));
  const float b1 = 1.0f - aatt, b2 = 1.0f - arel;
  const float s0 = b1 * b1, s1 = b1 * b2, s2 = b2 * b2;

  const fvec4* A4 = (const fvec4*)(audio) + (size_t)rec * 8;
  float gr[32];
#pragma unroll
  for (int i = 0; i < 8; ++i) {
    fvec4 v = A4[i];
#pragma unroll
    for (int j = 0; j < 4; ++j)
      gr[4 * i + j] =
          fmaxf(fmaf(K, __builtin_log2f(fabsf(v[j]) + 1e-8f), Cc), 0.0f);
  }
  if ((rec & (RECS_PER_CH - 1)) == 0) gr[0] = 0.0f;  // t==0: scan makes no update

  half8 h[5];
#pragma unroll
  for (int q = 0; q < 8; ++q) {
    // pair (4q,4q+1): att line (A,b1), rel line (R,b2); outer sample is later.
    float A0 = aatt * gr[4*q],     R0 = arel * gr[4*q];
    float A1 = aatt * gr[4*q + 1], R1 = arel * gr[4*q + 1];
    float u0 = fmaf(b1, A0, A1);                               // slope s0
    float um = fmaxf(fmaf(b1, R0, A1), fmaf(b2, A0, R1));      // slope s1
    float u2 = fmaf(b2, R0, R1);                               // slope s2
    float A2 = aatt * gr[4*q + 2], R2 = arel * gr[4*q + 2];
    float A3 = aatt * gr[4*q + 3], R3 = arel * gr[4*q + 3];
    float v0 = fmaf(b1, A2, A3);
    float vm = fmaxf(fmaf(b1, R2, A3), fmaf(b2, A2, R3));
    float v2 = fmaf(b2, R2, R3);
    // quad = vpair ∘ upair : w_k = max_{i+j=k}(v_i + s_i*u_j)
    float w0 = fmaf(s0, u0, v0);
    float w1 = fmaxf(fmaf(s0, um, v0), fmaf(s1, u0, vm));
    float w2 = fmax3f(fmaf(s0, u2, v0), fmaf(s1, um, vm), fmaf(s2, u0, v2));
    float w3 = fmaxf(fmaf(s1, u2, vm), fmaf(s2, um, v2));
    float w4 = fmaf(s2, u2, v2);
    h[0][q] = (half_t)w0; h[1][q] = (half_t)w1; h[2][q] = (half_t)w2;
    h[3][q] = (half_t)w3; h[4][q] = (half_t)w4;
  }
  half8* dst = recs + (size_t)rec * 5;
#pragma unroll
  for (int j = 0; j < 5; ++j) dst[j] = h[j];
}

__global__ __launch_bounds__(64) void comp_kernel(
    const float* __restrict__ audio,
    const half8* __restrict__ recs,
    const float* __restrict__ p_thr,
    const float* __restrict__ p_ratio,
    const float* __restrict__ p_att,
    const float* __restrict__ p_rel,
    const float* __restrict__ p_mk,
    float* __restrict__ out, int total_chunks) {
  const int tid = blockIdx.x * blockDim.x + threadIdx.x;
  if (tid >= total_chunks) return;
  const int CPC = T_LEN / C_CHUNK;
  const int ch = tid / CPC;
  const int t0 = (tid - ch * CPC) * C_CHUNK;

  const float thr = p_thr[0];
  const float r1  = 1.0f - 1.0f / p_ratio[0];
  const float K   = 6.0205999132796239f * r1;
  const float Cc  = -thr * r1;
  const float L2E = 1.4426950408889634f;
  const float aatt = 1.0f - __builtin_exp2f(-L2E / (p_att[0] * 48000.0f));
  const float arel = 1.0f - __builtin_exp2f(-L2E / (p_rel[0] * 48000.0f));
  const float b1 = 1.0f - aatt, b2 = 1.0f - arel;
  const float s0 = b1 * b1, s1 = b1 * b2, s2 = b2 * b2;
  const float S0 = s0 * s0, S1 = s0 * s1, S2 = s1 * s1, S3 = s1 * s2, S4 = s2 * s2;
  const float EK  = 0.16609640474436813f;       // log2(10)/20
  const float emk = p_mk[0] * EK;

  float g = 0.0f;

  // ---- Warm-up: composed quad steps, depth-4 modulo pipeline over records.
  int start = t0 - W_WARM;
  if (start < 0) start = 0;
  const int nrec = (t0 - start) >> 5;            // multiple of 4 (W/32=384, C/32=32)
  if (nrec > 0) {
    const half8* P = recs + ((size_t)ch * RECS_PER_CH + (start >> 5)) * 5;
    half8 bA[5], bB[5], bC[5], bD[5];
    auto ld = [&](half8 (&b)[5], int r) {
      const half8* p = P + 5 * r;
#pragma unroll
      for (int i = 0; i < 5; ++i) b[i] = p[i];
    };
    auto proc = [&](const half8 (&b)[5]) {
#pragma unroll
      for (int q = 0; q < 8; ++q) {
        float l0 = fmaf(S0, g, (float)b[0][q]);
        float l1 = fmaf(S1, g, (float)b[1][q]);
        float l2 = fmaf(S2, g, (float)b[2][q]);
        float l3 = fmaf(S3, g, (float)b[3][q]);
        float l4 = fmaf(S4, g, (float)b[4][q]);
        g = fmax3f(fmax3f(l0, l1, l2), l3, l4);
      }
    };
    ld(bA, 0); ld(bB, 1); ld(bC, 2);
#pragma unroll 1
    for (int r = 0; r + 4 <= nrec; r += 4) {
      // overrun loads reach record t0/32+2 < RECS_PER_CH: in-bounds, unused
      ld(bD, r + 3); proc(bA);
      ld(bA, r + 4); proc(bB);
      ld(bB, r + 5); proc(bC);
      ld(bC, r + 6); proc(bD);
    }
  }

  // ---- Output region: per-sample, gr computed inline from audio. ----
  const fvec4* Ap = (const fvec4*)(audio + (size_t)ch * T_LEN + t0);
  fvec4* Op = (fvec4*)(out + (size_t)ch * T_LEN + t0);
  const bool zfix = (t0 == 0);

  fvec4 a0[8], a1[8];
  auto lda = [&](fvec4 (&ab)[8], int b) {
#pragma unroll
    for (int i = 0; i < 8; ++i) ab[i] = Ap[8 * b + i];
  };
  auto emit = [&](const fvec4 (&ab)[8], int b, bool first) {
    fvec4 r[8];
#pragma unroll
    for (int s = 0; s < 32; ++s) {
      float x = ab[s >> 2][s & 3];
      float ax = fabsf(x) + 1e-8f;
      float grv = fmaxf(fmaf(K, __builtin_log2f(ax), Cc), 0.0f);
      if (first && s == 0 && zfix) grv = 0.0f;   // t==0: g stays 0
      float d = grv - g;
      g = fmaxf(fmaf(aatt, d, g), fmaf(arel, d, g));
      float mag = ax * __builtin_exp2f(fmaf(-EK, g, emk));
      float o = copysignf(mag, x);
      r[s >> 2][s & 3] = (x == 0.0f) ? 0.0f : o;
    }
#pragma unroll
    for (int i = 0; i < 8; ++i) Op[8 * b + i] = r[i];
  };

  const int NB = C_CHUNK / 32;     // 32 blocks
  lda(a0, 0);
#pragma unroll 1
  for (int b = 0; b < NB; b += 2) {
    lda(a1, b + 1);
    emit(a0, b, b == 0);
    int b2 = (b + 2 < NB) ? b + 2 : NB - 1;      // clamp: no OOB at channel end
    lda(a0, b2);
    emit(a1, b + 1, false);
  }
}

extern "C" void kernel_launch(void* const* d_in, const int* in_sizes, int n_in,
                              void* d_out, int out_size, void* d_ws, size_t ws_size,
                              hipStream_t stream) {
  const float* audio   = (const float*)d_in[0];
  const float* p_thr   = (const float*)d_in[1];
  const float* p_ratio = (const float*)d_in[2];
  const float* p_att   = (const float*)d_in[3];
  const float* p_rel   = (const float*)d_in[4];
  const float* p_mk    = (const float*)d_in[5];
  float* outp = (float*)d_out;

  const int n = in_sizes[0];                 // 16 * 2^20
  const int nrec_total = n / 32;             // 524288 records, 80 B each = 42 MB
  const int total_chunks = n / C_CHUNK;      // 16384
  half8* recs = (half8*)d_ws;                // fits: ws_size >= 64 MB

  pre_kernel<<<(nrec_total + 255) / 256, 256, 0, stream>>>(
      audio, p_thr, p_ratio, p_att, p_rel, recs, nrec_total);
  comp_kernel<<<(total_chunks + 63) / 64, 64, 0, stream>>>(
      audio, recs, p_thr, p_ratio, p_att, p_rel, p_mk, outp, total_chunks);
}